// Round 8
// baseline (31.205 us; speedup 1.0000x reference)
//
#include <hip/hip_runtime.h>

// GradLoss: mean((sobelx(t)-sobelx(o))^2) + mean((sobely(t)-sobely(o))^2)
//         = mean(sobelx(d)^2) + mean(sobely(d)^2), d = t - o   (linearity)
//
// Persistent pipelined kernel (T3-lite): 256 blocks (1/CU) x 512 threads.
// Each block: 4 consecutive 16-row tiles of one image, double-buffered LDS
// (2 x (o+t) x 18x512 floats = 144 KB). Per tile: issue next tile's
// global_load_lds DMAs FIRST, then compute current tile from LDS, then
// __syncthreads() (its vmcnt(0) drain is pre-satisfied by the overlap).
// Tail: last-finished block reduces 256 partials (R6-proven pattern).

#define BATCH 32
#define HH 512
#define WW 512
#define TR 16                        // output rows per tile
#define NRW (TR + 2)                 // staged rows per tile
#define TPB 512                      // 8 waves
#define NBLK 256                     // 1 block/CU, 4 tiles each
#define TPB_W (TPB / 64)

typedef const __attribute__((address_space(1))) void* gas_ptr;
typedef __attribute__((address_space(3))) void* las_ptr;

__device__ __forceinline__ void async_copy16(const float* g, float* l) {
    __builtin_amdgcn_global_load_lds((gas_ptr)(const void*)g,
                                     (las_ptr)(void*)l, 16, 0, 0);
}

__global__ __launch_bounds__(TPB) void sobel_loss_kernel(
    const float* __restrict__ out_img,
    const float* __restrict__ tgt_img,
    float* __restrict__ partials,
    unsigned* __restrict__ counter,
    float* __restrict__ result)
{
    __shared__ float tile[2][2][NRW * WW];   // [dbuf][o/t] = 144 KB
    __shared__ float wsum[TPB_W];
    __shared__ int   lastflag;

    const int tid  = threadIdx.x;
    const int lane = tid & 63;
    const int wv   = tid >> 6;               // 0..7
    const int b    = blockIdx.x;             // 0..255
    const int img  = b >> 3;                 // 8 blocks per image
    const int strip0 = (b & 7) * 4;          // 4 consecutive strips per block
    const size_t base = (size_t)img * HH * WW;

    // ---- async stage of one tile into buffer dbuf ----
    auto stage = [&](int dbuf, int strip) {
        const int y0  = strip * TR;
        const int top = (strip == 0);
        const int bot = (strip == 31);
        const int srcRow0 = top ? 0 : y0 - 1;
        const int ldsRow0 = top ? 1 : 0;
        const int nchunk  = (NRW - top - bot) * 2;   // 1KB chunks per array
        const float* osrc = out_img + base + (size_t)srcRow0 * WW;
        const float* tsrc = tgt_img + base + (size_t)srcRow0 * WW;
        float* od = &tile[dbuf][0][ldsRow0 * WW];
        float* td = &tile[dbuf][1][ldsRow0 * WW];
        for (int c = wv; c < nchunk; c += TPB_W) {
            const int off = c * 256 + lane * 4;      // uniform + lane*16B
            async_copy16(osrc + off, od + off);
            async_copy16(tsrc + off, td + off);
        }
        // zero never-staged image-edge halo rows (addresses disjoint from DMA)
        if (top) {
            if (tid < 128)       *(float4*)&tile[dbuf][0][tid * 4] = make_float4(0,0,0,0);
            else if (tid < 256)  *(float4*)&tile[dbuf][1][(tid-128) * 4] = make_float4(0,0,0,0);
        }
        if (bot) {
            if (tid < 128)       *(float4*)&tile[dbuf][0][(NRW-1)*WW + tid * 4] = make_float4(0,0,0,0);
            else if (tid < 256)  *(float4*)&tile[dbuf][1][(NRW-1)*WW + (tid-128) * 4] = make_float4(0,0,0,0);
        }
    };

    stage(0, strip0);
    __syncthreads();

    float acc = 0.f;

#define ROWLOAD(dst, R)                                                        \
    {                                                                          \
        const float4 o4 = *(const float4*)&ot[(R) * WW + cb];                  \
        const float4 t4 = *(const float4*)&tt[(R) * WW + cb];                  \
        dst = make_float4(t4.x - o4.x, t4.y - o4.y, t4.z - o4.z, t4.w - o4.w); \
    }
#define ROWPASS(hs, hd, d, R)                                                  \
    {                                                                          \
        const float svL = __shfl(s255, (R), 64);                               \
        const float svR = __shfl(s256, (R), 64);                               \
        float dl = __shfl_up((d).w, 1, 64);                                    \
        float dr = __shfl_down((d).x, 1, 64);                                  \
        if (lane == 0)  dl = h ? svL : 0.f;                                    \
        if (lane == 63) dr = h ? 0.f : svR;                                    \
        hs.x = fmaf(2.f, (d).x, dl + (d).y);      hd.x = (d).y - dl;           \
        hs.y = fmaf(2.f, (d).y, (d).x + (d).z);   hd.y = (d).z - (d).x;        \
        hs.z = fmaf(2.f, (d).z, (d).y + (d).w);   hd.z = (d).w - (d).y;        \
        hs.w = fmaf(2.f, (d).w, (d).z + dr);      hd.w = dr - (d).z;           \
    }
#define ACCUM(hsT, hdT, hsM, hdM, hsB, hdB)                                    \
    {                                                                          \
        float gx, gy;                                                          \
        gx = fmaf(2.f, hdM.x, hdT.x + hdB.x); gy = hsT.x - hsB.x;              \
        acc = fmaf(gx, gx, acc); acc = fmaf(gy, gy, acc);                      \
        gx = fmaf(2.f, hdM.y, hdT.y + hdB.y); gy = hsT.y - hsB.y;              \
        acc = fmaf(gx, gx, acc); acc = fmaf(gy, gy, acc);                      \
        gx = fmaf(2.f, hdM.z, hdT.z + hdB.z); gy = hsT.z - hsB.z;              \
        acc = fmaf(gx, gx, acc); acc = fmaf(gy, gy, acc);                      \
        gx = fmaf(2.f, hdM.w, hdT.w + hdB.w); gy = hsT.w - hsB.w;              \
        acc = fmaf(gx, gx, acc); acc = fmaf(gy, gy, acc);                      \
    }

    for (int t = 0; t < 4; ++t) {
        if (t < 3) stage((t + 1) & 1, strip0 + t + 1);   // overlap next stage

        const float* ot = &tile[t & 1][0][0];
        const float* tt = &tile[t & 1][1][0];

        // seam d-values for the 18 rows (lane r holds row r's cols 255/256)
        float s255 = 0.f, s256 = 0.f;
        if (lane < NRW) {
            s255 = tt[lane * WW + 255] - ot[lane * WW + 255];
            s256 = tt[lane * WW + 256] - ot[lane * WW + 256];
        }

        // wave wv owns output rows 2wv, 2wv+1 -> LDS rows 2wv .. 2wv+3
        const int R0 = 2 * wv;
        #pragma unroll
        for (int h = 0; h < 2; ++h) {
            const int cb = (h << 8) + lane * 4;
            float4 d0, d1, d2;
            float4 hs0, hd0, hs1, hd1, hs2, hd2;
            ROWLOAD(d0, R0 + 0); ROWPASS(hs0, hd0, d0, R0 + 0);
            ROWLOAD(d1, R0 + 1); ROWPASS(hs1, hd1, d1, R0 + 1);
            ROWLOAD(d2, R0 + 2); ROWPASS(hs2, hd2, d2, R0 + 2);
            ACCUM(hs0, hd0, hs1, hd1, hs2, hd2);
            ROWLOAD(d0, R0 + 3); ROWPASS(hs0, hd0, d0, R0 + 3);
            ACCUM(hs1, hd1, hs2, hd2, hs0, hd0);
        }
        __syncthreads();   // next buffer ready (drained under compute); buf reuse safe
    }
#undef ROWLOAD
#undef ROWPASS
#undef ACCUM

    // ---- block reduce -> partial; last-finished block reduces all ----
    #pragma unroll
    for (int off = 32; off > 0; off >>= 1)
        acc += __shfl_down(acc, off, 64);
    if (lane == 0) wsum[wv] = acc;
    __syncthreads();
    if (tid == 0) {
        float s = 0.f;
        #pragma unroll
        for (int k = 0; k < TPB_W; ++k) s += wsum[k];
        __hip_atomic_store(&partials[b], s, __ATOMIC_RELEASE,
                           __HIP_MEMORY_SCOPE_AGENT);
        const unsigned old = __hip_atomic_fetch_add(counter, 1u,
                                                    __ATOMIC_ACQ_REL,
                                                    __HIP_MEMORY_SCOPE_AGENT);
        lastflag = (old == NBLK - 1);
    }
    __syncthreads();

    if (lastflag) {
        float s = (tid < NBLK)
            ? __hip_atomic_load(&partials[tid], __ATOMIC_RELAXED,
                                __HIP_MEMORY_SCOPE_AGENT)
            : 0.f;
        #pragma unroll
        for (int off = 32; off > 0; off >>= 1)
            s += __shfl_down(s, off, 64);
        if (lane == 0) wsum[wv] = s;
        __syncthreads();
        if (tid == 0) {
            float v = 0.f;
            #pragma unroll
            for (int k = 0; k < TPB_W; ++k) v += wsum[k];
            result[0] = v * (1.0f / ((float)BATCH * HH * WW));
        }
    }
}

extern "C" void kernel_launch(void* const* d_in, const int* in_sizes, int n_in,
                              void* d_out, int out_size, void* d_ws, size_t ws_size,
                              hipStream_t stream) {
    (void)in_sizes; (void)n_in; (void)ws_size; (void)out_size;
    const float* out_img = (const float*)d_in[0];   // "output"
    const float* tgt_img = (const float*)d_in[1];   // "target"
    float* partials   = (float*)d_ws;               // NBLK floats
    unsigned* counter = (unsigned*)((char*)d_ws + NBLK * sizeof(float));
    float* res = (float*)d_out;

    hipMemsetAsync(counter, 0, sizeof(unsigned), stream);
    sobel_loss_kernel<<<NBLK, TPB, 0, stream>>>(out_img, tgt_img,
                                                partials, counter, res);
}

// Round 9
// 18.621 us; speedup vs baseline: 1.6758x; 1.6758x over previous
//
#include <hip/hip_runtime.h>

// GradLoss: mean((sobelx(t)-sobelx(o))^2) + mean((sobely(t)-sobely(o))^2)
//         = mean(sobelx(d)^2) + mean(sobely(d)^2), d = t - o   (linearity)
//
// Stage1: each wave owns FULL 512-col rows (8 cols/lane = 2 float4 slots);
//   the slot boundary is within-lane, so only 2 shuffles per row (lane halo,
//   zeroed at image edges) — no seams, no LDS, no barriers in the hot path.
//   RW=4 output rows/wave (6 rows loaded, halo rows re-hit L2/L3).
//   ALL state in macro-generated NAMED variables: no arrays -> no scratch
//   (the R6 failure). Loads pipelined 4 rows ahead of compute.
//   4096 waves / 1024 blocks / 16 waves-per-CU. One partial per block.
// Stage2: 1 block reduces 1024 partials. Two-dispatch frame (proven fastest;
//   same-address atomic tails measured at 14-50 ns each are worse).

#define BATCH 32
#define HH 512
#define WW 512
#define RW 4                         // output rows per wave
#define TPB 256
#define NBLK 1024                    // 4 waves per block
#define SPI (HH / RW)                // 128 strips per image

__global__ __launch_bounds__(TPB) void sobel_partial_kernel(
    const float* __restrict__ out_img,
    const float* __restrict__ tgt_img,
    float* __restrict__ partials)
{
    const int tid  = threadIdx.x;
    const int lane = tid & 63;
    const int wv   = tid >> 6;
    // XCD swizzle: contiguous 128-block (4-image) chunk per XCD
    const int b    = (blockIdx.x & 7) * (NBLK / 8) + (blockIdx.x >> 3);
    const int w    = b * (TPB / 64) + wv;          // 0..4095
    const int img  = w >> 7;                       // / SPI
    const int y0   = (w & (SPI - 1)) * RW;
    const size_t base = (size_t)img * HH * WW;
    const float* ob = out_img + base + (lane << 3);
    const float* tb = tgt_img + base + (lane << 3);

    float acc = 0.f;

#define DECLROW(j) float4 oA##j, oB##j, tA##j, tB##j, dA##j, dB##j,            \
                          hsA##j, hdA##j, hsB##j, hdB##j;

#define LOADR(j) {                                                             \
    const int gc = min(max(y0 - 1 + (j), 0), HH - 1);                          \
    const float* orow_ = ob + (size_t)gc * WW;                                 \
    const float* trow_ = tb + (size_t)gc * WW;                                 \
    oA##j = *(const float4*)orow_;       oB##j = *(const float4*)(orow_ + 4);  \
    tA##j = *(const float4*)trow_;       tB##j = *(const float4*)(trow_ + 4);  }

#define DIFFH(j) {                                                             \
    const float m_ = ((unsigned)(y0 - 1 + (j)) < (unsigned)HH) ? 1.f : 0.f;    \
    dA##j = make_float4(m_*(tA##j.x-oA##j.x), m_*(tA##j.y-oA##j.y),            \
                        m_*(tA##j.z-oA##j.z), m_*(tA##j.w-oA##j.w));           \
    dB##j = make_float4(m_*(tB##j.x-oB##j.x), m_*(tB##j.y-oB##j.y),            \
                        m_*(tB##j.z-oB##j.z), m_*(tB##j.w-oB##j.w));           \
    float dl_ = __shfl_up(dB##j.w, 1, 64);   if (lane == 0)  dl_ = 0.f;        \
    float dr_ = __shfl_down(dA##j.x, 1, 64); if (lane == 63) dr_ = 0.f;        \
    hsA##j.x = fmaf(2.f, dA##j.x, dl_ + dA##j.y);                              \
    hdA##j.x = dA##j.y - dl_;                                                  \
    hsA##j.y = fmaf(2.f, dA##j.y, dA##j.x + dA##j.z);                          \
    hdA##j.y = dA##j.z - dA##j.x;                                              \
    hsA##j.z = fmaf(2.f, dA##j.z, dA##j.y + dA##j.w);                          \
    hdA##j.z = dA##j.w - dA##j.y;                                              \
    hsA##j.w = fmaf(2.f, dA##j.w, dA##j.z + dB##j.x);                          \
    hdA##j.w = dB##j.x - dA##j.z;                                              \
    hsB##j.x = fmaf(2.f, dB##j.x, dA##j.w + dB##j.y);                          \
    hdB##j.x = dB##j.y - dA##j.w;                                              \
    hsB##j.y = fmaf(2.f, dB##j.y, dB##j.x + dB##j.z);                          \
    hdB##j.y = dB##j.z - dB##j.x;                                              \
    hsB##j.z = fmaf(2.f, dB##j.z, dB##j.y + dB##j.w);                          \
    hdB##j.z = dB##j.w - dB##j.y;                                              \
    hsB##j.w = fmaf(2.f, dB##j.w, dB##j.z + dr_);                              \
    hdB##j.w = dr_ - dB##j.z;                                                  }

#define VP1(S, a, bb, c) {                                                     \
    float gx_, gy_;                                                            \
    gx_ = fmaf(2.f, hd##S##bb.x, hd##S##a.x + hd##S##c.x);                     \
    gy_ = hs##S##a.x - hs##S##c.x;                                             \
    acc = fmaf(gx_, gx_, acc); acc = fmaf(gy_, gy_, acc);                      \
    gx_ = fmaf(2.f, hd##S##bb.y, hd##S##a.y + hd##S##c.y);                     \
    gy_ = hs##S##a.y - hs##S##c.y;                                             \
    acc = fmaf(gx_, gx_, acc); acc = fmaf(gy_, gy_, acc);                      \
    gx_ = fmaf(2.f, hd##S##bb.z, hd##S##a.z + hd##S##c.z);                     \
    gy_ = hs##S##a.z - hs##S##c.z;                                             \
    acc = fmaf(gx_, gx_, acc); acc = fmaf(gy_, gy_, acc);                      \
    gx_ = fmaf(2.f, hd##S##bb.w, hd##S##a.w + hd##S##c.w);                     \
    gy_ = hs##S##a.w - hs##S##c.w;                                             \
    acc = fmaf(gx_, gx_, acc); acc = fmaf(gy_, gy_, acc);                      }
#define VPASS(a, bb, c) VP1(A, a, bb, c) VP1(B, a, bb, c)

    DECLROW(0) DECLROW(1) DECLROW(2) DECLROW(3) DECLROW(4) DECLROW(5)

    LOADR(0) LOADR(1) LOADR(2) LOADR(3)      // 16 dwordx4 in flight
    DIFFH(0) DIFFH(1)
    LOADR(4)
    DIFFH(2) VPASS(0, 1, 2)
    LOADR(5)
    DIFFH(3) VPASS(1, 2, 3)
    DIFFH(4) VPASS(2, 3, 4)
    DIFFH(5) VPASS(3, 4, 5)

#undef DECLROW
#undef LOADR
#undef DIFFH
#undef VP1
#undef VPASS

    // wave reduce -> block reduce -> one plain store per block
    #pragma unroll
    for (int off = 32; off > 0; off >>= 1)
        acc += __shfl_down(acc, off, 64);
    __shared__ float wsum[TPB / 64];
    if (lane == 0) wsum[wv] = acc;
    __syncthreads();
    if (tid == 0)
        partials[b] = wsum[0] + wsum[1] + wsum[2] + wsum[3];
}

__global__ __launch_bounds__(TPB) void reduce_partials_kernel(
    const float* __restrict__ partials, float* __restrict__ out)
{
    const int tid = threadIdx.x;
    const float4 v = *(const float4*)(partials + tid * 4);   // 1024 = 256*4
    float s = (v.x + v.y) + (v.z + v.w);
    #pragma unroll
    for (int off = 32; off > 0; off >>= 1)
        s += __shfl_down(s, off, 64);
    __shared__ float wsum[TPB / 64];
    if ((tid & 63) == 0) wsum[tid >> 6] = s;
    __syncthreads();
    if (tid == 0)
        out[0] = (wsum[0] + wsum[1] + wsum[2] + wsum[3])
               * (1.0f / ((float)BATCH * HH * WW));
}

extern "C" void kernel_launch(void* const* d_in, const int* in_sizes, int n_in,
                              void* d_out, int out_size, void* d_ws, size_t ws_size,
                              hipStream_t stream) {
    (void)in_sizes; (void)n_in; (void)ws_size; (void)out_size;
    const float* out_img = (const float*)d_in[0];   // "output"
    const float* tgt_img = (const float*)d_in[1];   // "target"
    float* partials = (float*)d_ws;                 // NBLK floats
    float* res = (float*)d_out;

    sobel_partial_kernel<<<NBLK, TPB, 0, stream>>>(out_img, tgt_img, partials);
    reduce_partials_kernel<<<1, TPB, 0, stream>>>(partials, res);
}